// Round 2
// baseline (5985.741 us; speedup 1.0000x reference)
//
#include <hip/hip_runtime.h>

// TemporalGCN: px[t][k] = A_t^k x_t (k=0..3) via 3 atomic-scatter SPMV levels,
// then windowed combine with h[4][4] + ReLU -> out[N, T_out=8] (f32).

#define T_DIM 12
#define N_DIM 200000
#define E_DIM 3200000
#define KP1_DIM 4
#define P_DIM 4
#define T_OUT 8

// px layout in workspace: float px[T][KP1][N]  (12*4*200000*4B = 38.4 MB)

__global__ void init_px(const float* __restrict__ x, float* __restrict__ px) {
    const int total = T_DIM * KP1_DIM * N_DIM;
    for (int i = blockIdx.x * blockDim.x + threadIdx.x; i < total;
         i += gridDim.x * blockDim.x) {
        int n  = i % N_DIM;
        int tk = i / N_DIM;      // t*KP1 + k
        int k  = tk & 3;
        int t  = tk >> 2;
        px[i] = (k == 0) ? x[t * N_DIM + n] : 0.0f;
    }
}

// One k-level for ALL t's: y[t][k][row] += w * px[t][k-1][col]
__global__ void spmv_level(const int* __restrict__ edge_index,
                           const float* __restrict__ edge_weight,
                           float* __restrict__ px, int k) {
    const int total = T_DIM * E_DIM;   // 38.4M < 2^31
    for (int i = blockIdx.x * blockDim.x + threadIdx.x; i < total;
         i += gridDim.x * blockDim.x) {
        int e = i % E_DIM;
        int t = i / E_DIM;
        const int* ei = edge_index + t * 2 * E_DIM;
        int row = ei[e];             // segment target
        int col = ei[E_DIM + e];     // gather source
        float w = edge_weight[t * E_DIM + e];
        const float* vin = px + (t * KP1_DIM + (k - 1)) * N_DIM;
        float*       vout = px + (t * KP1_DIM + k) * N_DIM;
        atomicAdd(&vout[row], w * vin[col]);
    }
}

// out[n, t_out] = relu( sum_{p,k} h[k][p] * px[t_out+p][k][n] )
__global__ void combine_out(const float* __restrict__ px,
                            const float* __restrict__ h,
                            float* __restrict__ out) {
    // load h[4][4] (uniform -> scalar cached loads)
    float hh[KP1_DIM][P_DIM];
    #pragma unroll
    for (int k = 0; k < KP1_DIM; k++)
        #pragma unroll
        for (int p = 0; p < P_DIM; p++)
            hh[k][p] = h[k * P_DIM + p];

    for (int n = blockIdx.x * blockDim.x + threadIdx.x; n < N_DIM;
         n += gridDim.x * blockDim.x) {
        float acc[T_OUT];
        #pragma unroll
        for (int i = 0; i < T_OUT; i++) acc[i] = 0.0f;

        #pragma unroll
        for (int t = 0; t < T_DIM; t++) {
            #pragma unroll
            for (int k = 0; k < KP1_DIM; k++) {
                float val = px[(t * KP1_DIM + k) * N_DIM + n];
                #pragma unroll
                for (int p = 0; p < P_DIM; p++) {
                    int t_out = t - p;
                    if (t_out >= 0 && t_out < T_OUT)
                        acc[t_out] += hh[k][p] * val;
                }
            }
        }
        #pragma unroll
        for (int i = 0; i < T_OUT; i++)
            out[n * T_OUT + i] = fmaxf(acc[i], 0.0f);
    }
}

extern "C" void kernel_launch(void* const* d_in, const int* in_sizes, int n_in,
                              void* d_out, int out_size, void* d_ws, size_t ws_size,
                              hipStream_t stream) {
    const float* x           = (const float*)d_in[0];
    const int*   edge_index  = (const int*)d_in[1];
    const float* edge_weight = (const float*)d_in[2];
    const float* h           = (const float*)d_in[3];
    float* out = (float*)d_out;
    float* px  = (float*)d_ws;   // 38.4 MB

    init_px<<<2048, 256, 0, stream>>>(x, px);
    for (int k = 1; k < KP1_DIM; k++) {
        spmv_level<<<2048, 256, 0, stream>>>(edge_index, edge_weight, px, k);
    }
    combine_out<<<784, 256, 0, stream>>>(px, h, out);
}

// Round 3
// 2016.988 us; speedup vs baseline: 2.9677x; 2.9677x over previous
//
#include <hip/hip_runtime.h>

// TemporalGCN: px[t][k] = A_t^k x_t (k=0..3), then windowed combine with
// h[4][4] + ReLU -> out[N, T_out=8] (f32).
//
// Strategy: global f32 atomics are the bottleneck (~20G/s, memory-side RMW).
// Partition edges by 1024-row bucket once per t (count/scan/scatter, LDS
// histograms only), then each SPMV level is atomic-free: one block per
// (t,bucket) accumulates in LDS and writes back densely.

#define T_DIM 12
#define N_DIM 200000
#define E_DIM 3200000
#define KP1_DIM 4
#define P_DIM 4
#define T_OUT 8

#define RB 1024                 // rows per bucket
#define RSHIFT 10
#define B_CNT 196               // ceil(N/RB)
#define CHUNK 16384             // edges per partition block (256 thr * 64)
#define NCHUNK 196              // ceil(E/CHUNK)
#define COLMASK 0x3FFFF         // 18 bits (N < 2^18)

// ---------------- fast path kernels ----------------

__global__ void init_px_k0(const float* __restrict__ x, float* __restrict__ px) {
    const int total = T_DIM * N_DIM;
    for (int i = blockIdx.x * blockDim.x + threadIdx.x; i < total;
         i += gridDim.x * blockDim.x) {
        int n = i % N_DIM;
        int t = i / N_DIM;
        px[((size_t)t * KP1_DIM + 0) * N_DIM + n] = x[(size_t)t * N_DIM + n];
    }
}

__global__ void count_kernel(const int* __restrict__ edge_index,
                             unsigned int* __restrict__ cnt, int tbase) {
    int t_rel = blockIdx.x / NCHUNK;
    int chunk = blockIdx.x % NCHUNK;
    int t = tbase + t_rel;
    __shared__ unsigned int hist[B_CNT];
    if (threadIdx.x < B_CNT) hist[threadIdx.x] = 0;
    __syncthreads();
    const int* rows = edge_index + (size_t)t * 2 * E_DIM;
    int e0 = chunk * CHUNK + threadIdx.x;
    #pragma unroll 4
    for (int it = 0; it < CHUNK / 256; it++) {
        int e = e0 + it * 256;
        if (e < E_DIM) {
            int r = __builtin_nontemporal_load(&rows[e]);
            atomicAdd(&hist[r >> RSHIFT], 1u);
        }
    }
    __syncthreads();
    if (threadIdx.x < B_CNT)
        cnt[((size_t)t * NCHUNK + chunk) * B_CNT + threadIdx.x] = hist[threadIdx.x];
}

// per (t,bucket): turn per-chunk counts into per-chunk prefixes; emit totals
__global__ void scan_chunks(unsigned int* __restrict__ cnt,
                            unsigned int* __restrict__ tot, int tbase, int g) {
    int gid = blockIdx.x * blockDim.x + threadIdx.x;
    if (gid >= g * B_CNT) return;
    int t_rel = gid / B_CNT;
    int b = gid % B_CNT;
    int t = tbase + t_rel;
    unsigned int running = 0;
    for (int c = 0; c < NCHUNK; c++) {
        size_t idx = ((size_t)t * NCHUNK + c) * B_CNT + b;
        unsigned int v = cnt[idx];
        cnt[idx] = running;
        running += v;
    }
    tot[t * B_CNT + b] = running;
}

// per t: exclusive scan of bucket totals -> base
__global__ void scan_buckets(const unsigned int* __restrict__ tot,
                             unsigned int* __restrict__ base, int tbase) {
    int t = tbase + blockIdx.x;
    if (threadIdx.x == 0) {
        unsigned int run = 0;
        for (int b = 0; b < B_CNT; b++) {
            base[t * B_CNT + b] = run;
            run += tot[t * B_CNT + b];
        }
    }
}

__global__ void scatter_kernel(const int* __restrict__ edge_index,
                               const float* __restrict__ edge_weight,
                               const unsigned int* __restrict__ cnt,
                               const unsigned int* __restrict__ base,
                               uint2* __restrict__ pe, int tbase) {
    int t_rel = blockIdx.x / NCHUNK;
    int chunk = blockIdx.x % NCHUNK;
    int t = tbase + t_rel;
    __shared__ unsigned int off[B_CNT];
    if (threadIdx.x < B_CNT)
        off[threadIdx.x] = base[t * B_CNT + threadIdx.x] +
                           cnt[((size_t)t * NCHUNK + chunk) * B_CNT + threadIdx.x];
    __syncthreads();
    const int* rows = edge_index + (size_t)t * 2 * E_DIM;
    const int* cols = rows + E_DIM;
    const float* w  = edge_weight + (size_t)t * E_DIM;
    uint2* pet = pe + (size_t)t_rel * E_DIM;
    int e0 = chunk * CHUNK + threadIdx.x;
    for (int it = 0; it < CHUNK / 256; it++) {
        int e = e0 + it * 256;
        if (e < E_DIM) {
            int r = __builtin_nontemporal_load(&rows[e]);
            int c = __builtin_nontemporal_load(&cols[e]);
            float wv = __builtin_nontemporal_load(&w[e]);
            int b = r >> RSHIFT;
            unsigned int pos = atomicAdd(&off[b], 1u);
            uint2 p;
            p.x = ((unsigned int)(r & (RB - 1)) << 18) | (unsigned int)c;
            p.y = __float_as_uint(wv);
            pet[pos] = p;
        }
    }
}

// one block per (bucket, slot). slot->t, slot%8 keeps a t on one XCD so the
// gather source (px[t][k-1], 800KB) stays L2-resident.
__global__ void spmv_bucket(const uint2* __restrict__ pe,
                            float* __restrict__ px,
                            const unsigned int* __restrict__ base,
                            const unsigned int* __restrict__ tot,
                            int tbase, int g, int k, int SL) {
    int slot = blockIdx.x % SL;
    int bucket = blockIdx.x / SL;
    if (slot >= g) return;
    int t = tbase + slot;
    __shared__ float acc[RB];
    for (int i = threadIdx.x; i < RB; i += 256) acc[i] = 0.0f;
    __syncthreads();
    unsigned int start = base[t * B_CNT + bucket];
    unsigned int n_e   = tot[t * B_CNT + bucket];
    const unsigned long long* edges =
        (const unsigned long long*)(pe + (size_t)slot * E_DIM);
    const float* vin = px + ((size_t)t * KP1_DIM + (k - 1)) * N_DIM;
    for (unsigned int i = threadIdx.x; i < n_e; i += 256) {
        unsigned long long p = __builtin_nontemporal_load(&edges[start + i]);
        unsigned int pk = (unsigned int)p;
        float wv = __uint_as_float((unsigned int)(p >> 32));
        unsigned int col = pk & COLMASK;
        unsigned int rl  = pk >> 18;
        atomicAdd(&acc[rl], wv * vin[col]);
    }
    __syncthreads();
    int row0 = bucket * RB;
    int nrow = min(RB, N_DIM - row0);
    float* vout = px + ((size_t)t * KP1_DIM + k) * N_DIM + row0;
    for (int i = threadIdx.x; i < nrow; i += 256) vout[i] = acc[i];
}

// ---------------- fallback (atomic) kernels ----------------

__global__ void init_px_full(const float* __restrict__ x, float* __restrict__ px) {
    const int total = T_DIM * KP1_DIM * N_DIM;
    for (int i = blockIdx.x * blockDim.x + threadIdx.x; i < total;
         i += gridDim.x * blockDim.x) {
        int n  = i % N_DIM;
        int tk = i / N_DIM;
        int kk = tk & 3;
        int t  = tk >> 2;
        px[i] = (kk == 0) ? x[(size_t)t * N_DIM + n] : 0.0f;
    }
}

__global__ void spmv_level_atomic(const int* __restrict__ edge_index,
                                  const float* __restrict__ edge_weight,
                                  float* __restrict__ px, int k) {
    const int total = T_DIM * E_DIM;
    for (int i = blockIdx.x * blockDim.x + threadIdx.x; i < total;
         i += gridDim.x * blockDim.x) {
        int e = i % E_DIM;
        int t = i / E_DIM;
        const int* ei = edge_index + (size_t)t * 2 * E_DIM;
        int row = ei[e];
        int col = ei[E_DIM + e];
        float w = edge_weight[(size_t)t * E_DIM + e];
        const float* vin = px + ((size_t)t * KP1_DIM + (k - 1)) * N_DIM;
        float*       vout = px + ((size_t)t * KP1_DIM + k) * N_DIM;
        atomicAdd(&vout[row], w * vin[col]);
    }
}

// ---------------- combine ----------------

__global__ void combine_out(const float* __restrict__ px,
                            const float* __restrict__ h,
                            float* __restrict__ out) {
    float hh[KP1_DIM][P_DIM];
    #pragma unroll
    for (int k = 0; k < KP1_DIM; k++)
        #pragma unroll
        for (int p = 0; p < P_DIM; p++)
            hh[k][p] = h[k * P_DIM + p];

    for (int n = blockIdx.x * blockDim.x + threadIdx.x; n < N_DIM;
         n += gridDim.x * blockDim.x) {
        float acc[T_OUT];
        #pragma unroll
        for (int i = 0; i < T_OUT; i++) acc[i] = 0.0f;
        #pragma unroll
        for (int t = 0; t < T_DIM; t++) {
            #pragma unroll
            for (int k = 0; k < KP1_DIM; k++) {
                float val = px[((size_t)t * KP1_DIM + k) * N_DIM + n];
                #pragma unroll
                for (int p = 0; p < P_DIM; p++) {
                    int t_out = t - p;
                    if (t_out >= 0 && t_out < T_OUT)
                        acc[t_out] += hh[k][p] * val;
                }
            }
        }
        #pragma unroll
        for (int i = 0; i < T_OUT; i++)
            out[(size_t)n * T_OUT + i] = fmaxf(acc[i], 0.0f);
    }
}

// ---------------- launcher ----------------

static inline size_t align256(size_t x) { return (x + 255) & ~(size_t)255; }

extern "C" void kernel_launch(void* const* d_in, const int* in_sizes, int n_in,
                              void* d_out, int out_size, void* d_ws, size_t ws_size,
                              hipStream_t stream) {
    const float* x           = (const float*)d_in[0];
    const int*   edge_index  = (const int*)d_in[1];
    const float* edge_weight = (const float*)d_in[2];
    const float* h           = (const float*)d_in[3];
    float* out = (float*)d_out;

    char* ws = (char*)d_ws;
    const size_t px_bytes   = (size_t)T_DIM * KP1_DIM * N_DIM * 4;        // 38.4 MB
    const size_t cnt_bytes  = (size_t)T_DIM * NCHUNK * B_CNT * 4;        // 1.84 MB
    const size_t tb_bytes   = (size_t)T_DIM * B_CNT * 4;                 // 9.4 KB

    size_t off = 0;
    float* px = (float*)(ws + off);             off += align256(px_bytes);
    unsigned int* cnt  = (unsigned int*)(ws + off); off += align256(cnt_bytes);
    unsigned int* tot  = (unsigned int*)(ws + off); off += align256(tb_bytes);
    unsigned int* base = (unsigned int*)(ws + off); off += align256(tb_bytes);
    size_t fixed = off;
    const size_t per_t = (size_t)E_DIM * 8;     // packed uint2 per t

    int G = 0;
    if (ws_size > fixed) G = (int)((ws_size - fixed) / per_t);
    if (G > T_DIM) G = T_DIM;

    if (G >= 1) {
        uint2* pe = (uint2*)(ws + fixed);
        init_px_k0<<<2048, 256, 0, stream>>>(x, px);
        for (int tb = 0; tb < T_DIM; tb += G) {
            int g = min(G, T_DIM - tb);
            count_kernel<<<g * NCHUNK, 256, 0, stream>>>(edge_index, cnt, tb);
            scan_chunks<<<(g * B_CNT + 255) / 256, 256, 0, stream>>>(cnt, tot, tb, g);
            scan_buckets<<<g, 64, 0, stream>>>(tot, base, tb);
            scatter_kernel<<<g * NCHUNK, 256, 0, stream>>>(edge_index, edge_weight,
                                                           cnt, base, pe, tb);
            int SL = ((g + 7) / 8) * 8;
            for (int k = 1; k < KP1_DIM; k++) {
                spmv_bucket<<<B_CNT * SL, 256, 0, stream>>>(pe, px, base, tot,
                                                            tb, g, k, SL);
            }
        }
    } else {
        // workspace too small for partition path: atomic fallback
        init_px_full<<<2048, 256, 0, stream>>>(x, px);
        for (int k = 1; k < KP1_DIM; k++)
            spmv_level_atomic<<<2048, 256, 0, stream>>>(edge_index, edge_weight, px, k);
    }
    combine_out<<<784, 256, 0, stream>>>(px, h, out);
}